// Round 6
// baseline (335.136 us; speedup 1.0000x reference)
//
#include <hip/hip_runtime.h>

// GraphSAGE forward. CSR build + 4 fused level kernels + output projection.
//
// Invariants proven over rounds 2-5:
//  - Gather: GSIZE lanes per node read ONE full contiguous row per vmem
//    instruction (float2/float4); indices prefetched lane-parallel, shfl
//    broadcast; 4-edge unroll. Fragmented/strided row reads thrash L2
//    (round 3/4: FETCH 199-636MB).
//  - Stores: full contiguous rows of consecutive nodes per instruction
//    (round 4's scattered 16B chunks -> 206MB write-evict storm).
//  - GEMM phases: block-cooperative, barrier-separated, weights broadcast
//    from LDS. Round 6: register-tiled (float4 weight per k feeding 4 fmacs,
//    optional 2-row reuse), L3 at MINW=4 so LDS loads can pipeline.
//  - Algebraic cut: mean_agg(h)@Wa == mean_agg(h@Wa). L3 emits g=h3@Wa4 only;
//    L4 gathers 128B g-rows, relu folded into its We GEMM input read.

__global__ __launch_bounds__(256) void k_count(const int* __restrict__ edst,
                                               int* __restrict__ deg, int E) {
    int t = blockIdx.x * blockDim.x + threadIdx.x;
    if (t < E) atomicAdd(&deg[edst[t]], 1);
}

__global__ __launch_bounds__(256) void k_blocksum(const int* __restrict__ deg,
                                                  int* __restrict__ bsums, int N) {
    __shared__ int s[256];
    int t = threadIdx.x;
    int base = blockIdx.x * 1024 + t * 4;
    int v = 0;
#pragma unroll
    for (int j = 0; j < 4; j++) { int idx = base + j; if (idx < N) v += deg[idx]; }
    s[t] = v; __syncthreads();
    for (int o = 128; o > 0; o >>= 1) { if (t < o) s[t] += s[t + o]; __syncthreads(); }
    if (t == 0) bsums[blockIdx.x] = s[0];
}

__global__ __launch_bounds__(256) void k_scantop(int* __restrict__ bsums, int NB) {
    __shared__ int s[256];
    int t = threadIdx.x;
    int v = (t < NB) ? bsums[t] : 0;
    s[t] = v; __syncthreads();
    for (int o = 1; o < 256; o <<= 1) {
        int x = (t >= o) ? s[t - o] : 0;
        __syncthreads();
        s[t] += x;
        __syncthreads();
    }
    if (t < NB) bsums[t] = s[t] - v;
}

__global__ __launch_bounds__(256) void k_scanfinal(const int* __restrict__ deg,
                                                   const int* __restrict__ bsums,
                                                   int* __restrict__ offsets,
                                                   int* __restrict__ cursor,
                                                   float* __restrict__ inv_cnt,
                                                   int N, int E) {
    __shared__ int s[256];
    int t = threadIdx.x, b = blockIdx.x;
    int base = b * 1024 + t * 4;
    int d[4]; int lsum = 0;
#pragma unroll
    for (int j = 0; j < 4; j++) { int idx = base + j; d[j] = (idx < N) ? deg[idx] : 0; lsum += d[j]; }
    s[t] = lsum; __syncthreads();
    for (int o = 1; o < 256; o <<= 1) {
        int x = (t >= o) ? s[t - o] : 0;
        __syncthreads();
        s[t] += x;
        __syncthreads();
    }
    int p = bsums[b] + s[t] - lsum;
#pragma unroll
    for (int j = 0; j < 4; j++) {
        int idx = base + j;
        if (idx < N) {
            offsets[idx] = p;
            cursor[idx] = p;
            inv_cnt[idx] = 1.0f / (float)(d[j] > 0 ? d[j] : 1);
            p += d[j];
        }
    }
    if (b == 0 && t == 0) offsets[N] = E;
}

__global__ __launch_bounds__(256) void k_scatter(const int* __restrict__ esrc,
                                                 const int* __restrict__ edst,
                                                 int* __restrict__ cursor,
                                                 int* __restrict__ csr, int E) {
    int t = blockIdx.x * blockDim.x + threadIdx.x;
    if (t < E) {
        int d = edst[t];
        int pos = atomicAdd(&cursor[d], 1);
        csr[pos] = esrc[t];
    }
}

// Cooperative register-tiled GEMM phase, LDS->LDS. Thread tile: NR rows x VEC
// cols. Per k: 1 vector weight read + NR broadcast m reads -> NR*VEC fmac.
// Output relu always (both A and H stash phases want it).
template <int NPB, int K, int DC, int PADI, int PADO, int VEC, int NR, bool RELU_IN>
__device__ inline void gemm_lds(const float* sIn, const float* sW, float* sOut, int t) {
    constexpr int CQ = DC / VEC;
    constexpr int RB = NPB / NR;
    constexpr int TILES = RB * CQ;
    static_assert(RB * NR == NPB && CQ * VEC == DC, "tiling mismatch");
    for (int tile = t; tile < TILES; tile += 512) {
        int rb = tile / CQ, q = tile % CQ;
        float acc[NR][VEC] = {};
#pragma unroll
        for (int k = 0; k < K; ++k) {
            float w[VEC];
            if constexpr (VEC == 4) *(float4*)w = *(const float4*)&sW[k * DC + 4 * q];
            else                    *(float2*)w = *(const float2*)&sW[k * DC + 2 * q];
#pragma unroll
            for (int jr = 0; jr < NR; ++jr) {
                float mv = sIn[(rb * NR + jr) * PADI + k];
                if constexpr (RELU_IN) mv = fmaxf(mv, 0.f);
#pragma unroll
                for (int o = 0; o < VEC; ++o) acc[jr][o] += mv * w[o];
            }
        }
#pragma unroll
        for (int jr = 0; jr < NR; ++jr) {
            float r[VEC];
#pragma unroll
            for (int o = 0; o < VEC; ++o) r[o] = fmaxf(acc[jr][o], 0.f);
            if constexpr (VEC == 4) *(float4*)&sOut[(rb * NR + jr) * PADO + 4 * q] = *(float4*)r;
            else                    *(float2*)&sOut[(rb * NR + jr) * PADO + 2 * q] = *(float2*)r;
        }
    }
}

// Same, LDS->global (contiguous consecutive-node rows per instruction).
template <int NPB, int K, int DC, int PADI, int VEC, int NR, bool RELU_IN, bool RELU_OUT>
__device__ inline void gemm_out(const float* sIn, const float* sW,
                                float* __restrict__ dst, int nodebase, int N, int t) {
    constexpr int CQ = DC / VEC;
    constexpr int RB = NPB / NR;
    constexpr int TILES = RB * CQ;
    static_assert(RB * NR == NPB && CQ * VEC == DC, "tiling mismatch");
    for (int tile = t; tile < TILES; tile += 512) {
        int rb = tile / CQ, q = tile % CQ;
        float acc[NR][VEC] = {};
#pragma unroll
        for (int k = 0; k < K; ++k) {
            float w[VEC];
            if constexpr (VEC == 4) *(float4*)w = *(const float4*)&sW[k * DC + 4 * q];
            else                    *(float2*)w = *(const float2*)&sW[k * DC + 2 * q];
#pragma unroll
            for (int jr = 0; jr < NR; ++jr) {
                float mv = sIn[(rb * NR + jr) * PADI + k];
                if constexpr (RELU_IN) mv = fmaxf(mv, 0.f);
#pragma unroll
                for (int o = 0; o < VEC; ++o) acc[jr][o] += mv * w[o];
            }
        }
#pragma unroll
        for (int jr = 0; jr < NR; ++jr) {
            int node = nodebase + rb * NR + jr;
            if (node < N) {
                float r[VEC];
#pragma unroll
                for (int o = 0; o < VEC; ++o)
                    r[o] = RELU_OUT ? fmaxf(acc[jr][o], 0.f) : acc[jr][o];
                if constexpr (VEC == 4) *(float4*)&dst[(size_t)node * DC + 4 * q] = *(float4*)r;
                else                    *(float2*)&dst[(size_t)node * DC + 2 * q] = *(float2*)r;
            }
        }
    }
}

// One block = NPB nodes. gather-mean -> [A] -> H -> {global | stash+G}.
template <int DIN, int DMID, int DOUT, int GSIZE, int PADM, int PADA,
          bool HAS_WA, int DG, int MINW>
__global__ __launch_bounds__(512, MINW) void k_level(
    const float* __restrict__ hprev, float* __restrict__ outbuf,
    const int* __restrict__ offsets, const int* __restrict__ csr,
    const float* __restrict__ inv_cnt,
    const float* __restrict__ Wa, const float* __restrict__ We,
    const float* __restrict__ Wg, int N) {
    constexpr int WAVES = 8;
    constexpr int NPG = 64 / GSIZE;
    constexpr int NPB = WAVES * NPG;
    constexpr int VG = (DIN >= 32) ? DIN / GSIZE : 1;  // floats per lane per row
    static_assert(DIN < 32 || VG == 2 || VG == 4, "gather vec width");

    __shared__ alignas(16) float sWa[HAS_WA ? DIN * DMID : 1];
    __shared__ alignas(16) float sWe[DMID * DOUT];
    __shared__ alignas(16) float sWg[(DG > 0) ? DOUT * DG : 1];
    __shared__ alignas(16) float sM[NPB * PADM];
    __shared__ alignas(16) float sA[HAS_WA ? NPB * PADA : 1];

    if constexpr (HAS_WA)
        for (int i = threadIdx.x; i < DIN * DMID; i += 512) sWa[i] = Wa[i];
    for (int i = threadIdx.x; i < DMID * DOUT; i += 512) sWe[i] = We[i];
    if constexpr (DG > 0)
        for (int i = threadIdx.x; i < DOUT * DG; i += 512) sWg[i] = Wg[i];
    __syncthreads();

    const int t    = threadIdx.x;
    const int lane = t & 63;
    const int wid  = t >> 6;
    const int g    = lane / GSIZE;
    const int lg   = lane % GSIZE;
    const int srcb = g * GSIZE;
    const int slot = wid * NPG + g;

    for (int base = blockIdx.x * NPB; base < N; base += gridDim.x * NPB) {
        int node = base + slot;
        // ---- gather + mean: full contiguous row per vmem instruction ----
        if (node < N) {
            int start = offsets[node], end = offsets[node + 1];
            if constexpr (VG == 4) {
                float4 acc = make_float4(0.f, 0.f, 0.f, 0.f);
                const float4* hp = (const float4*)hprev;
                for (int bb = start; bb < end; bb += GSIZE) {
                    int cnt = min(GSIZE, end - bb);
                    int sidx = (lg < cnt) ? csr[bb + lg] : 0;
                    int i = 0;
                    for (; i + 4 <= cnt; i += 4) {
                        int s0 = __shfl(sidx, srcb + i);
                        int s1 = __shfl(sidx, srcb + i + 1);
                        int s2 = __shfl(sidx, srcb + i + 2);
                        int s3 = __shfl(sidx, srcb + i + 3);
                        float4 v0 = hp[(size_t)s0 * GSIZE + lg];
                        float4 v1 = hp[(size_t)s1 * GSIZE + lg];
                        float4 v2 = hp[(size_t)s2 * GSIZE + lg];
                        float4 v3 = hp[(size_t)s3 * GSIZE + lg];
                        acc.x += (v0.x + v1.x) + (v2.x + v3.x);
                        acc.y += (v0.y + v1.y) + (v2.y + v3.y);
                        acc.z += (v0.z + v1.z) + (v2.z + v3.z);
                        acc.w += (v0.w + v1.w) + (v2.w + v3.w);
                    }
                    for (; i < cnt; ++i) {
                        int s0 = __shfl(sidx, srcb + i);
                        float4 v0 = hp[(size_t)s0 * GSIZE + lg];
                        acc.x += v0.x; acc.y += v0.y; acc.z += v0.z; acc.w += v0.w;
                    }
                }
                float ic = inv_cnt[node];
                acc.x *= ic; acc.y *= ic; acc.z *= ic; acc.w *= ic;
                *(float4*)&sM[slot * PADM + 4 * lg] = acc;
            } else if constexpr (VG == 2) {
                float2 acc = make_float2(0.f, 0.f);
                const float2* hp = (const float2*)hprev;
                for (int bb = start; bb < end; bb += GSIZE) {
                    int cnt = min(GSIZE, end - bb);
                    int sidx = (lg < cnt) ? csr[bb + lg] : 0;
                    int i = 0;
                    for (; i + 4 <= cnt; i += 4) {
                        int s0 = __shfl(sidx, srcb + i);
                        int s1 = __shfl(sidx, srcb + i + 1);
                        int s2 = __shfl(sidx, srcb + i + 2);
                        int s3 = __shfl(sidx, srcb + i + 3);
                        float2 v0 = hp[(size_t)s0 * GSIZE + lg];
                        float2 v1 = hp[(size_t)s1 * GSIZE + lg];
                        float2 v2 = hp[(size_t)s2 * GSIZE + lg];
                        float2 v3 = hp[(size_t)s3 * GSIZE + lg];
                        acc.x += (v0.x + v1.x) + (v2.x + v3.x);
                        acc.y += (v0.y + v1.y) + (v2.y + v3.y);
                    }
                    for (; i < cnt; ++i) {
                        int s0 = __shfl(sidx, srcb + i);
                        float2 v0 = hp[(size_t)s0 * GSIZE + lg];
                        acc.x += v0.x; acc.y += v0.y;
                    }
                }
                float ic = inv_cnt[node];
                *(float2*)&sM[slot * PADM + 2 * lg] = make_float2(acc.x * ic, acc.y * ic);
            } else {  // DIN == 3
                float a1 = 0.f;
                for (int bb = start; bb < end; bb += GSIZE) {
                    int cnt = min(GSIZE, end - bb);
                    int sidx = (lg < cnt) ? csr[bb + lg] : 0;
                    int i = 0;
                    for (; i + 4 <= cnt; i += 4) {
                        int s0 = __shfl(sidx, srcb + i);
                        int s1 = __shfl(sidx, srcb + i + 1);
                        int s2 = __shfl(sidx, srcb + i + 2);
                        int s3 = __shfl(sidx, srcb + i + 3);
                        if (lg < DIN) {
                            a1 += hprev[(size_t)s0 * DIN + lg] + hprev[(size_t)s1 * DIN + lg]
                                + hprev[(size_t)s2 * DIN + lg] + hprev[(size_t)s3 * DIN + lg];
                        }
                    }
                    for (; i < cnt; ++i) {
                        int s0 = __shfl(sidx, srcb + i);
                        if (lg < DIN) a1 += hprev[(size_t)s0 * DIN + lg];
                    }
                }
                if (lg < DIN) sM[slot * PADM + lg] = a1 * inv_cnt[node];
            }
        }
        __syncthreads();

        if constexpr (HAS_WA) {
            // A: sA = relu(sM @ Wa)
            constexpr int NR_A = (NPB * DMID >= 4096) ? 2 : 1;
            gemm_lds<NPB, DIN, DMID, PADM, PADA, 4, NR_A, false>(sM, sWa, sA, t);
            __syncthreads();
            if constexpr (DG > 0) {
                // H: stash h = relu(sA @ We) into sM, then G: h @ Wg -> global
                gemm_lds<NPB, DMID, DOUT, PADA, PADM, 4, 1, false>(sA, sWe, sM, t);
                __syncthreads();
                gemm_out<NPB, DOUT, DG, PADM, 4, 1, false, false>(sM, sWg, outbuf, base, N, t);
            } else {
                constexpr int NR_H = (NPB * DOUT >= 4096) ? 2 : 1;
                gemm_out<NPB, DMID, DOUT, PADA, 4, NR_H, false, true>(sA, sWe, outbuf, base, N, t);
            }
        } else {
            // relu folded into the We GEMM's input read
            gemm_out<NPB, DMID, DOUT, PADM, 4, 1, true, true>(sM, sWe, outbuf, base, N, t);
        }
        __syncthreads();  // slab reuse next tile
    }
}

__global__ __launch_bounds__(256) void k_out(const float* __restrict__ h,
                                             const int* __restrict__ nodes,
                                             const float* __restrict__ Wout,
                                             float* __restrict__ out, int B) {
    __shared__ float sW[32 * 40];
    for (int i = threadIdx.x; i < 32 * 40; i += blockDim.x) sW[i] = Wout[i];
    __syncthreads();
    int t = blockIdx.x * blockDim.x + threadIdx.x;
    if (t >= B * 40) return;
    int i = t / 40, c = t - i * 40;
    const float* e = h + (long)nodes[i] * 32;
    float s = 0.f;
#pragma unroll
    for (int k = 0; k < 32; k++) s += e[k] * sW[k * 40 + c];
    out[t] = s;
}

extern "C" void kernel_launch(void* const* d_in, const int* in_sizes, int n_in,
                              void* d_out, int out_size, void* d_ws, size_t ws_size,
                              hipStream_t stream) {
    const float* raw  = (const float*)d_in[0];
    const int* nodes  = (const int*)d_in[1];
    const int* esrc   = (const int*)d_in[2];
    const int* edst   = (const int*)d_in[3];
    const float* Wa1 = (const float*)d_in[4];
    const float* Wa2 = (const float*)d_in[5];
    const float* Wa3 = (const float*)d_in[6];
    const float* Wa4 = (const float*)d_in[7];
    const float* We1 = (const float*)d_in[8];
    const float* We2 = (const float*)d_in[9];
    const float* We3 = (const float*)d_in[10];
    const float* We4 = (const float*)d_in[11];
    const float* Wout = (const float*)d_in[12];
    float* out = (float*)d_out;

    int N = in_sizes[1];   // 50000
    int E = in_sizes[2];   // 850000
    int B = N;

    char* p = (char*)d_ws;
    auto alloc = [&](size_t bytes) -> char* {
        char* r = p;
        p += (bytes + 255) & ~(size_t)255;
        return r;
    };
    int*   deg     = (int*)alloc((size_t)N * 4);
    int*   offsets = (int*)alloc((size_t)(N + 1) * 4);
    int*   cursor  = (int*)alloc((size_t)N * 4);
    float* inv_cnt = (float*)alloc((size_t)N * 4);
    int NB = (N + 1023) / 1024;
    int*   bsums   = (int*)alloc((size_t)NB * 4);
    int*   csr     = (int*)alloc((size_t)E * 4);
    float* hA      = (float*)alloc((size_t)N * 64 * 4);
    float* hB      = (float*)alloc((size_t)N * 64 * 4);
    (void)ws_size; (void)n_in; (void)out_size;

    hipMemsetAsync(deg, 0, (size_t)N * 4, stream);
    int eb = (E + 255) / 256;
    k_count<<<eb, 256, 0, stream>>>(edst, deg, E);
    k_blocksum<<<NB, 256, 0, stream>>>(deg, bsums, N);
    k_scantop<<<1, 256, 0, stream>>>(bsums, NB);
    k_scanfinal<<<NB, 256, 0, stream>>>(deg, bsums, offsets, cursor, inv_cnt, N, E);
    k_scatter<<<eb, 256, 0, stream>>>(esrc, edst, cursor, csr, E);

    auto blocksFor = [](int n, int npb) {
        int b = (n + npb - 1) / npb;
        return b < 2048 ? b : 2048;
    };
    // L1: raw(3) -> h1(32) in hB.  NPB=128.
    k_level<3, 32, 32, 4, 4, 34, true, 0, 8>
        <<<blocksFor(N, 128), 512, 0, stream>>>(raw, hB, offsets, csr, inv_cnt,
                                                Wa1, We1, nullptr, N);
    // L2: h1(32) -> h2(64) in hA.  GSIZE=16 (float2 rows), NPB=32.
    k_level<32, 32, 64, 16, 34, 34, true, 0, 8>
        <<<blocksFor(N, 32), 512, 0, stream>>>(hB, hA, offsets, csr, inv_cnt,
                                               Wa2, We2, nullptr, N);
    // L3: h2(64) -> h3(64) -> emit g=h3@Wa4 (32) into hB.
    //     GSIZE=16 (float4 rows), NPB=32, MINW=4 for LDS pipelining headroom.
    k_level<64, 64, 64, 16, 68, 68, true, 32, 4>
        <<<blocksFor(N, 32), 512, 0, stream>>>(hA, hB, offsets, csr, inv_cnt,
                                               Wa3, We3, Wa4, N);
    // L4: gather g(32); h4 = relu(relu(mean) @ We4) in hA (Wa absorbed).
    k_level<32, 32, 32, 16, 34, 1, false, 0, 8>
        <<<blocksFor(N, 32), 512, 0, stream>>>(hB, hA, offsets, csr, inv_cnt,
                                               nullptr, We4, nullptr, N);

    k_out<<<(B * 40 + 255) / 256, 256, 0, stream>>>(hA, nodes, Wout, out, B);
}